// Round 17
// baseline (946.991 us; speedup 1.0000x reference)
//
#include <hip/hip_runtime.h>

typedef __attribute__((ext_vector_type(8))) short bf16x8;
typedef __attribute__((ext_vector_type(4))) float f32x4;
typedef unsigned short u16;

#define D_MODEL 1024
#define SEQ 512
#define BATCH 4
#define NH 16
#define FF 4096
#define NLAYER 6
#define NTOKS 2048

__device__ __forceinline__ u16 f2bf(float f) {
  unsigned int u = __float_as_uint(f);
  u += 0x7fffu + ((u >> 16) & 1u);
  return (u16)(u >> 16);
}
__device__ __forceinline__ float bf2f(u16 v) {
  return __uint_as_float(((unsigned int)v) << 16);
}

__device__ __forceinline__ void gload16(const void* g, void* lds) {
  __builtin_amdgcn_global_load_lds((const __attribute__((address_space(1))) void*)g,
                                   (__attribute__((address_space(3))) void*)lds, 16, 0, 0);
}

// ---------------- positional encoding: bf16 residual out only ----------------
__global__ __launch_bounds__(256) void posenc_k(const float* __restrict__ x, u16* __restrict__ hb) {
  int row = blockIdx.x;
  int s = row & (SEQ - 1);
  int t = threadIdx.x;
  float4 v = *(const float4*)(x + (size_t)row * D_MODEL + t * 4);
  float r[4] = {v.x, v.y, v.z, v.w};
#pragma unroll
  for (int j = 0; j < 4; ++j) {
    int d = t * 4 + j;
    int p = d >> 1;
    float ang = (float)s * exp2f((float)p * (-2.0f / 1024.0f) * 13.287712379549449f);
    r[j] += (d & 1) ? cosf(ang) : sinf(ang);
  }
  ushort4 ob;
  ob.x = f2bf(r[0]); ob.y = f2bf(r[1]); ob.z = f2bf(r[2]); ob.w = f2bf(r[3]);
  *(ushort4*)(hb + (size_t)row * D_MODEL + t * 4) = ob;
}

// ---------------- weight transpose+convert ----------------
#define WTP 72
__device__ __forceinline__ void wconv_body(const float* __restrict__ src, u16* __restrict__ dst,
                                           int K, int N, float scale, int nb, int kb) {
  __shared__ u16 tile[64 * WTP];
  const int t = threadIdx.x;
#pragma unroll
  for (int rr = 0; rr < 4; ++rr) {
    int k = (t >> 4) + rr * 16;
    int n4 = (t & 15) * 4;
    float4 v = *(const float4*)(src + (size_t)(kb + k) * N + nb + n4);
    tile[(n4 + 0) * WTP + k] = f2bf(v.x * scale);
    tile[(n4 + 1) * WTP + k] = f2bf(v.y * scale);
    tile[(n4 + 2) * WTP + k] = f2bf(v.z * scale);
    tile[(n4 + 3) * WTP + k] = f2bf(v.w * scale);
  }
  __syncthreads();
#pragma unroll
  for (int rr = 0; rr < 2; ++rr) {
    int n = (t >> 3) + rr * 32;
    int kq = (t & 7) * 8;
    uint4 v = *(const uint4*)&tile[n * WTP + kq];
    *(uint4*)&dst[(size_t)(nb + n) * K + kb + kq] = v;
  }
}

__global__ __launch_bounds__(256) void wconv_qkv_k(const float* __restrict__ Wq,
                                                   const float* __restrict__ Wk,
                                                   const float* __restrict__ Wv,
                                                   u16* __restrict__ dst) {
  int z = blockIdx.z, l = z / 3, which = z % 3;
  const float* src = (which == 0 ? Wq : which == 1 ? Wk : Wv) + (size_t)l * 1024 * 1024;
  u16* d = dst + (size_t)l * 3072 * 1024 + (size_t)which * 1024 * 1024;
  float scale = (which == 0) ? 0.125f : 1.0f;
  wconv_body(src, d, 1024, 1024, scale, blockIdx.x * 64, blockIdx.y * 64);
}

__global__ __launch_bounds__(256) void wconv_gen_k(const float* __restrict__ W, u16* __restrict__ dst,
                                                   int K, int N) {
  int z = blockIdx.z;
  wconv_body(W + (size_t)z * K * N, dst + (size_t)z * N * K, K, N, 1.0f,
             blockIdx.x * 64, blockIdx.y * 64);
}

__global__ __launch_bounds__(256) void bqkv_k(const float* bq, const float* bk, const float* bv,
                                              float* o) {
  int i = blockIdx.x * 256 + threadIdx.x;  // 18432
  int l = i / 3072, j = i % 3072;
  float v = (j < 1024) ? bq[l * 1024 + j] * 0.125f
                       : (j < 2048 ? bk[l * 1024 + j - 1024] : bv[l * 1024 + j - 2048]);
  o[i] = v;
}

// ---------------- GEMM 128x128x32, 4 waves, 4-buf depth-3 vmcnt pipeline ----------------
// KSPLIT>1: writes bf16 partials (z-th slab of Cv as u16). VTFUSE: V third -> transposed vt.
template <int OBF, int RELU, int KSPLIT, int VTFUSE>
__global__ __launch_bounds__(256) void gemm128_k(const u16* __restrict__ A, const u16* __restrict__ Bt,
                                                 const float* __restrict__ bias, void* __restrict__ Cv,
                                                 int N, int K, u16* __restrict__ vtout) {
  __shared__ u16 As[4][128 * 32];
  __shared__ u16 Bs[4][128 * 32];
  const int t = threadIdx.x, lane = t & 63, wave = t >> 6;
  const int wm = wave >> 1, wn = wave & 1;
  const int lrow = lane & 15, lgrp = lane >> 4;

  const int GX = N >> 7;
  const int nwg = GX * 16;
  int flat = blockIdx.y * GX + blockIdx.x;
  int q = nwg >> 3, r = nwg & 7, xcd = flat & 7, pos = flat >> 3;
  int logical = (xcd < r ? xcd * (q + 1) : r * (q + 1) + (xcd - r) * q) + pos;
  const int m0 = (logical & 15) * 128, n0 = (logical >> 4) * 128;

  const int kseg = K / KSPLIT;
  const int koff = (KSPLIT > 1) ? blockIdx.z * kseg : 0;

  f32x4 acc[4][4];
#pragma unroll
  for (int i = 0; i < 4; ++i)
#pragma unroll
    for (int j = 0; j < 4; ++j) acc[i][j] = (f32x4){0.f, 0.f, 0.f, 0.f};

  const u16* Ag = A + (size_t)m0 * K + koff;
  const u16* Bg = Bt + (size_t)n0 * K + koff;

  auto stage = [&](int buf, int k0) {
#pragma unroll
    for (int rr = 0; rr < 2; ++rr) {
      int s = rr * 256 + t;
      int row = s >> 2, cst = s & 3;
      int csrc = cst ^ ((row >> 1) & 3);
      gload16(Ag + (size_t)row * K + k0 + csrc * 8, &As[buf][s * 8]);
    }
#pragma unroll
    for (int rr = 0; rr < 2; ++rr) {
      int s = rr * 256 + t;
      int row = s >> 2, cst = s & 3;
      int csrc = cst ^ ((row >> 1) & 3);
      gload16(Bg + (size_t)row * K + k0 + csrc * 8, &Bs[buf][s * 8]);
    }
  };

  const int nk = kseg / 32;
  stage(0, 0);
  stage(1, 32);
  stage(2, 64);
  for (int tt = 0; tt < nk; ++tt) {
    if (tt + 2 < nk) asm volatile("s_waitcnt vmcnt(8)" ::: "memory");
    else if (tt + 1 < nk) asm volatile("s_waitcnt vmcnt(4)" ::: "memory");
    else asm volatile("s_waitcnt vmcnt(0)" ::: "memory");
    __builtin_amdgcn_s_barrier();
    __builtin_amdgcn_sched_barrier(0);
    if (tt + 3 < nk) stage((tt + 3) & 3, (tt + 3) * 32);
    const int cur = tt & 3;
    bf16x8 af[4], bfr[4];
#pragma unroll
    for (int i = 0; i < 4; ++i) {
      int row = wm * 64 + i * 16 + lrow;
      int sl = lgrp ^ ((row >> 1) & 3);
      af[i] = *(const bf16x8*)&As[cur][row * 32 + sl * 8];
    }
#pragma unroll
    for (int j = 0; j < 4; ++j) {
      int row = wn * 64 + j * 16 + lrow;
      int sl = lgrp ^ ((row >> 1) & 3);
      bfr[j] = *(const bf16x8*)&Bs[cur][row * 32 + sl * 8];
    }
    __builtin_amdgcn_s_setprio(1);
#pragma unroll
    for (int i = 0; i < 4; ++i)
#pragma unroll
      for (int j = 0; j < 4; ++j)
        acc[i][j] = __builtin_amdgcn_mfma_f32_16x16x32_bf16(af[i], bfr[j], acc[i][j], 0, 0, 0);
    __builtin_amdgcn_s_setprio(0);
  }

  const size_t outoff = (KSPLIT > 1) ? (size_t)blockIdx.z * NTOKS * N : 0;
#pragma unroll
  for (int j = 0; j < 4; ++j) {
    int col = n0 + wn * 64 + j * 16 + lrow;
    float bv = (KSPLIT == 1 || blockIdx.z == 0) ? bias[col] : 0.f;
#pragma unroll
    for (int i = 0; i < 4; ++i) {
      int rowb = m0 + wm * 64 + i * 16 + lgrp * 4;
      if (VTFUSE && col >= 2048) {
        int dg = col - 2048;
        int bb = rowb >> 9, s0 = rowb & 511;
        ushort4 wv;
        wv.x = f2bf(acc[i][j][0] + bv);
        wv.y = f2bf(acc[i][j][1] + bv);
        wv.z = f2bf(acc[i][j][2] + bv);
        wv.w = f2bf(acc[i][j][3] + bv);
        *(ushort4*)&vtout[((size_t)(bb * 1024 + dg)) * 512 + s0] = wv;
      } else if (KSPLIT > 1) {
#pragma unroll
        for (int r = 0; r < 4; ++r)
          ((u16*)Cv)[outoff + (size_t)(rowb + r) * N + col] = f2bf(acc[i][j][r] + bv);
      } else {
#pragma unroll
        for (int r = 0; r < 4; ++r) {
          float v = acc[i][j][r] + bv;
          if (RELU) v = fmaxf(v, 0.f);
          if (OBF)
            ((u16*)Cv)[(size_t)(rowb + r) * N + col] = f2bf(v);
          else
            ((float*)Cv)[(size_t)(rowb + r) * N + col] = v;
        }
      }
    }
  }
}

// ---------------- fused flash attention, NO-MAX softmax + gload_lds K/V staging ----------------
// K/V tiles: linear [64][64] LDS (8 slots of 16B per row), global_load_lds width-16,
// both-sides XOR swizzle: source slot csrc = cst ^ (row&7); read slot (kk*4+lgrp) ^ (lrow&7)
// -> 2-way bank alias only (free). Ps path and all 3 barriers unchanged (r10 lesson).
#define KPAD 72
__global__ __launch_bounds__(256) void attn_k(const u16* __restrict__ qkv, const u16* __restrict__ vt,
                                              const float* __restrict__ mask, u16* __restrict__ o) {
  __shared__ u16 Ks[64 * 64];
  __shared__ u16 Vs[64 * 64];
  __shared__ u16 Ps[64 * KPAD];
  const int t = threadIdx.x;
  const int lane = t & 63, wave = t >> 6;
  const int lrow = lane & 15, lgrp = lane >> 4;
  const int qb = blockIdx.x;
  const int bh = blockIdx.y;
  const int b = bh >> 4, hh = bh & 15;

  bf16x8 qf[2];
  const int qrow0 = qb * 64 + wave * 16;
#pragma unroll
  for (int kk = 0; kk < 2; ++kk)
    qf[kk] = *(const bf16x8*)(qkv + (size_t)(b * SEQ + qrow0 + lrow) * 3072 +
                              hh * 64 + kk * 32 + lgrp * 8);

  float lsum[4];
  f32x4 oacc[4];
#pragma unroll
  for (int r = 0; r < 4; ++r) lsum[r] = 0.f;
#pragma unroll
  for (int dn = 0; dn < 4; ++dn) oacc[dn] = (f32x4){0.f, 0.f, 0.f, 0.f};

  for (int it = 0; it < 8; ++it) {
    const int kv0 = it * 64;
    // stage K (64 kv-rows x 64 d) and V^T (64 d-rows x 64 kv): 512 slots each, 2/thread
#pragma unroll
    for (int half = 0; half < 2; ++half) {
      int s = half * 256 + t;
      int row = s >> 3, cst = s & 7;
      int csrc = cst ^ (row & 7);
      gload16(qkv + (size_t)(b * SEQ + kv0 + row) * 3072 + 1024 + hh * 64 + csrc * 8, &Ks[s * 8]);
      gload16(vt + (size_t)(bh * 64 + row) * 512 + kv0 + csrc * 8, &Vs[s * 8]);
    }
    __syncthreads();  // drains vmcnt -> K/V staged

    f32x4 s[4];
#pragma unroll
    for (int nt = 0; nt < 4; ++nt) s[nt] = (f32x4){0.f, 0.f, 0.f, 0.f};
    __builtin_amdgcn_s_setprio(1);
#pragma unroll
    for (int nt = 0; nt < 4; ++nt)
#pragma unroll
      for (int kk = 0; kk < 2; ++kk) {
        int krow = nt * 16 + lrow;
        int sl = (kk * 4 + lgrp) ^ (lrow & 7);
        bf16x8 kf = *(const bf16x8*)&Ks[krow * 64 + sl * 8];
        s[nt] = __builtin_amdgcn_mfma_f32_16x16x32_bf16(qf[kk], kf, s[nt], 0, 0, 0);
      }
    __builtin_amdgcn_s_setprio(0);
    float mv[4];
#pragma unroll
    for (int nt = 0; nt < 4; ++nt) mv[nt] = mask[b * SEQ + kv0 + nt * 16 + lrow] * -1e9f;

#pragma unroll
    for (int r = 0; r < 4; ++r) {
      float p0 = __expf(s[0][r] + mv[0]);
      float p1 = __expf(s[1][r] + mv[1]);
      float p2 = __expf(s[2][r] + mv[2]);
      float p3 = __expf(s[3][r] + mv[3]);
      lsum[r] += (p0 + p1) + (p2 + p3);
      int prow = wave * 16 + lgrp * 4 + r;
      Ps[prow * KPAD + 0 + lrow] = f2bf(p0);
      Ps[prow * KPAD + 16 + lrow] = f2bf(p1);
      Ps[prow * KPAD + 32 + lrow] = f2bf(p2);
      Ps[prow * KPAD + 48 + lrow] = f2bf(p3);
    }
    __syncthreads();
    __builtin_amdgcn_s_setprio(1);
#pragma unroll
    for (int kk = 0; kk < 2; ++kk) {
      bf16x8 pf = *(const bf16x8*)(&Ps[(wave * 16 + lrow) * KPAD + kk * 32 + lgrp * 8]);
#pragma unroll
      for (int dn = 0; dn < 4; ++dn) {
        int drow = dn * 16 + lrow;
        int sl = (kk * 4 + lgrp) ^ (lrow & 7);
        bf16x8 vf = *(const bf16x8*)&Vs[drow * 64 + sl * 8];
        oacc[dn] = __builtin_amdgcn_mfma_f32_16x16x32_bf16(pf, vf, oacc[dn], 0, 0, 0);
      }
    }
    __builtin_amdgcn_s_setprio(0);
    __syncthreads();
  }
#pragma unroll
  for (int r = 0; r < 4; ++r) {
    lsum[r] += __shfl_xor(lsum[r], 1);
    lsum[r] += __shfl_xor(lsum[r], 2);
    lsum[r] += __shfl_xor(lsum[r], 4);
    lsum[r] += __shfl_xor(lsum[r], 8);
  }
#pragma unroll
  for (int dn = 0; dn < 4; ++dn)
#pragma unroll
    for (int r = 0; r < 4; ++r) {
      int qrow = qrow0 + lgrp * 4 + r;
      o[(size_t)(b * SEQ + qrow) * D_MODEL + hh * 64 + dn * 16 + lrow] =
          f2bf(oacc[dn][r] / lsum[r]);
    }
}

// ---------------- bf16 residual + P bf16 split-K partials + LayerNorm ----------------
template <int P, int FINAL>
__global__ __launch_bounds__(256) void ln_k(const u16* __restrict__ res, const u16* __restrict__ parts,
                                            const float* __restrict__ g, const float* __restrict__ be,
                                            void* __restrict__ outv) {
  __shared__ float red[8];
  const int row = blockIdx.x, t = threadIdx.x;
  ushort4 va = *(const ushort4*)(res + (size_t)row * D_MODEL + t * 4);
  float x0 = bf2f(va.x), x1 = bf2f(va.y), x2 = bf2f(va.z), x3 = bf2f(va.w);
#pragma unroll
  for (int p = 0; p < P; ++p) {
    ushort4 vp = *(const ushort4*)(parts + (size_t)p * NTOKS * D_MODEL + (size_t)row * D_MODEL + t * 4);
    x0 += bf2f(vp.x); x1 += bf2f(vp.y); x2 += bf2f(vp.z); x3 += bf2f(vp.w);
  }
  float s = x0 + x1 + x2 + x3;
  float s2 = x0 * x0 + x1 * x1 + x2 * x2 + x3 * x3;
#pragma unroll
  for (int off = 1; off < 64; off <<= 1) {
    s += __shfl_xor(s, off);
    s2 += __shfl_xor(s2, off);
  }
  const int wave = t >> 6, lane = t & 63;
  if (lane == 0) { red[wave] = s; red[4 + wave] = s2; }
  __syncthreads();
  s = red[0] + red[1] + red[2] + red[3];
  s2 = red[4] + red[5] + red[6] + red[7];
  float mean = s * (1.f / D_MODEL);
  float var = s2 * (1.f / D_MODEL) - mean * mean;
  float inv = rsqrtf(var + 1e-6f);
  float4 vg = *(const float4*)(g + t * 4);
  float4 ve = *(const float4*)(be + t * 4);
  float r0 = (x0 - mean) * inv * vg.x + ve.x;
  float r1 = (x1 - mean) * inv * vg.y + ve.y;
  float r2 = (x2 - mean) * inv * vg.z + ve.z;
  float r3 = (x3 - mean) * inv * vg.w + ve.w;
  if (FINAL) {
    float4 r = {r0, r1, r2, r3};
    *(float4*)((float*)outv + (size_t)row * D_MODEL + t * 4) = r;
  } else {
    ushort4 w;
    w.x = f2bf(r0); w.y = f2bf(r1); w.z = f2bf(r2); w.w = f2bf(r3);
    *(ushort4*)((u16*)outv + (size_t)row * D_MODEL + t * 4) = w;
  }
}

// ---------------- launch ----------------
extern "C" void kernel_launch(void* const* d_in, const int* in_sizes, int n_in,
                              void* d_out, int out_size, void* d_ws, size_t ws_size,
                              hipStream_t stream) {
  const float* x = (const float*)d_in[0];
  const float* mask = (const float*)d_in[1];
  const float* Wq = (const float*)d_in[2];
  const float* bq = (const float*)d_in[3];
  const float* Wk = (const float*)d_in[4];
  const float* bk = (const float*)d_in[5];
  const float* Wv = (const float*)d_in[6];
  const float* bv = (const float*)d_in[7];
  const float* Wo = (const float*)d_in[8];
  const float* bo = (const float*)d_in[9];
  const float* W1 = (const float*)d_in[10];
  const float* b1 = (const float*)d_in[11];
  const float* W2 = (const float*)d_in[12];
  const float* b2 = (const float*)d_in[13];
  const float* g1 = (const float*)d_in[14];
  const float* be1 = (const float*)d_in[15];
  const float* g2 = (const float*)d_in[16];
  const float* be2 = (const float*)d_in[17];
  float* out = (float*)d_out;

  const size_t NTOK = (size_t)BATCH * SEQ;  // 2048
  const size_t ACT = NTOK * D_MODEL;        // 2M
  char* w = (char*)d_ws;
  u16* op = (u16*)w;        w += ACT * 2 * 4;      // split-K bf16 partials x4
  u16* hb = (u16*)w;        w += ACT * 2;          // bf16 residual stream (layer in)
  u16* h1b = (u16*)w;       w += ACT * 2;          // bf16 post-LN1
  u16* qkvb = (u16*)w;      w += NTOK * 3072 * 2;
  u16* vt_ = (u16*)w;       w += ACT * 2;
  u16* obb = (u16*)w;       w += ACT * 2;
  u16* tb = (u16*)w;        w += NTOK * FF * 2;
  u16* wqkv_all = (u16*)w;  w += (size_t)NLAYER * 3072 * 1024 * 2;
  u16* wo_all = (u16*)w;    w += (size_t)NLAYER * 1024 * 1024 * 2;
  u16* w1_all = (u16*)w;    w += (size_t)NLAYER * 4096 * 1024 * 2;
  u16* w2_all = (u16*)w;    w += (size_t)NLAYER * 1024 * 4096 * 2;
  float* bqkv_all = (float*)w; w += (size_t)NLAYER * 3072 * 4;

  posenc_k<<<(int)NTOK, 256, 0, stream>>>(x, hb);
  wconv_qkv_k<<<dim3(16, 16, 18), 256, 0, stream>>>(Wq, Wk, Wv, wqkv_all);
  wconv_gen_k<<<dim3(16, 16, 6), 256, 0, stream>>>(Wo, wo_all, 1024, 1024);
  wconv_gen_k<<<dim3(64, 16, 6), 256, 0, stream>>>(W1, w1_all, 1024, 4096);
  wconv_gen_k<<<dim3(16, 64, 6), 256, 0, stream>>>(W2, w2_all, 4096, 1024);
  bqkv_k<<<72, 256, 0, stream>>>(bq, bk, bv, bqkv_all);

  for (int l = 0; l < NLAYER; ++l) {
    const u16* wqkv_t = wqkv_all + (size_t)l * 3072 * 1024;
    const u16* wo_t = wo_all + (size_t)l * 1024 * 1024;
    const u16* w1_t = w1_all + (size_t)l * 4096 * 1024;
    const u16* w2_t = w2_all + (size_t)l * 1024 * 4096;
    const float* bqkvl = bqkv_all + (size_t)l * 3072;
    const float* bol = bo + (size_t)l * D_MODEL;
    const float* b1l = b1 + (size_t)l * FF;
    const float* b2l = b2 + (size_t)l * D_MODEL;
    const float* g1l = g1 + (size_t)l * D_MODEL;
    const float* be1l = be1 + (size_t)l * D_MODEL;
    const float* g2l = g2 + (size_t)l * D_MODEL;
    const float* be2l = be2 + (size_t)l * D_MODEL;

    gemm128_k<1, 0, 1, 1><<<dim3(24, 16), 256, 0, stream>>>(hb, wqkv_t, bqkvl, qkvb, 3072, 1024, vt_);
    attn_k<<<dim3(8, 64), 256, 0, stream>>>(qkvb, vt_, mask, obb);
    gemm128_k<0, 0, 4, 0><<<dim3(8, 16, 4), 256, 0, stream>>>(obb, wo_t, bol, op, 1024, 1024, nullptr);
    ln_k<4, 0><<<(int)NTOK, 256, 0, stream>>>(hb, op, g1l, be1l, h1b);
    gemm128_k<1, 1, 1, 0><<<dim3(32, 16), 256, 0, stream>>>(h1b, w1_t, b1l, tb, 4096, 1024, nullptr);
    gemm128_k<0, 0, 4, 0><<<dim3(8, 16, 4), 256, 0, stream>>>(tb, w2_t, b2l, op, 1024, 4096, nullptr);
    if (l == NLAYER - 1)
      ln_k<4, 1><<<(int)NTOK, 256, 0, stream>>>(h1b, op, g2l, be2l, out);
    else
      ln_k<4, 0><<<(int)NTOK, 256, 0, stream>>>(h1b, op, g2l, be2l, hb);
  }
}

// Round 18
// 943.243 us; speedup vs baseline: 1.0040x; 1.0040x over previous
//
#include <hip/hip_runtime.h>

typedef __attribute__((ext_vector_type(8))) short bf16x8;
typedef __attribute__((ext_vector_type(4))) float f32x4;
typedef __attribute__((ext_vector_type(8))) unsigned short u16x8;
typedef unsigned short u16;

#define D_MODEL 1024
#define SEQ 512
#define BATCH 4
#define NH 16
#define FF 4096
#define NLAYER 6
#define NTOKS 2048

__device__ __forceinline__ u16 f2bf(float f) {
  unsigned int u = __float_as_uint(f);
  u += 0x7fffu + ((u >> 16) & 1u);
  return (u16)(u >> 16);
}
__device__ __forceinline__ float bf2f(u16 v) {
  return __uint_as_float(((unsigned int)v) << 16);
}

__device__ __forceinline__ void gload16(const void* g, void* lds) {
  __builtin_amdgcn_global_load_lds((const __attribute__((address_space(1))) void*)g,
                                   (__attribute__((address_space(3))) void*)lds, 16, 0, 0);
}

// ---------------- positional encoding: bf16 residual out only ----------------
__global__ __launch_bounds__(256) void posenc_k(const float* __restrict__ x, u16* __restrict__ hb) {
  int row = blockIdx.x;
  int s = row & (SEQ - 1);
  int t = threadIdx.x;
  float4 v = *(const float4*)(x + (size_t)row * D_MODEL + t * 4);
  float r[4] = {v.x, v.y, v.z, v.w};
#pragma unroll
  for (int j = 0; j < 4; ++j) {
    int d = t * 4 + j;
    int p = d >> 1;
    float ang = (float)s * exp2f((float)p * (-2.0f / 1024.0f) * 13.287712379549449f);
    r[j] += (d & 1) ? cosf(ang) : sinf(ang);
  }
  ushort4 ob;
  ob.x = f2bf(r[0]); ob.y = f2bf(r[1]); ob.z = f2bf(r[2]); ob.w = f2bf(r[3]);
  *(ushort4*)(hb + (size_t)row * D_MODEL + t * 4) = ob;
}

// ---------------- weight transpose+convert ----------------
#define WTP 72
__device__ __forceinline__ void wconv_body(const float* __restrict__ src, u16* __restrict__ dst,
                                           int K, int N, float scale, int nb, int kb) {
  __shared__ u16 tile[64 * WTP];
  const int t = threadIdx.x;
#pragma unroll
  for (int rr = 0; rr < 4; ++rr) {
    int k = (t >> 4) + rr * 16;
    int n4 = (t & 15) * 4;
    float4 v = *(const float4*)(src + (size_t)(kb + k) * N + nb + n4);
    tile[(n4 + 0) * WTP + k] = f2bf(v.x * scale);
    tile[(n4 + 1) * WTP + k] = f2bf(v.y * scale);
    tile[(n4 + 2) * WTP + k] = f2bf(v.z * scale);
    tile[(n4 + 3) * WTP + k] = f2bf(v.w * scale);
  }
  __syncthreads();
#pragma unroll
  for (int rr = 0; rr < 2; ++rr) {
    int n = (t >> 3) + rr * 32;
    int kq = (t & 7) * 8;
    uint4 v = *(const uint4*)&tile[n * WTP + kq];
    *(uint4*)&dst[(size_t)(nb + n) * K + kb + kq] = v;
  }
}

__global__ __launch_bounds__(256) void wconv_qkv_k(const float* __restrict__ Wq,
                                                   const float* __restrict__ Wk,
                                                   const float* __restrict__ Wv,
                                                   u16* __restrict__ dst) {
  int z = blockIdx.z, l = z / 3, which = z % 3;
  const float* src = (which == 0 ? Wq : which == 1 ? Wk : Wv) + (size_t)l * 1024 * 1024;
  u16* d = dst + (size_t)l * 3072 * 1024 + (size_t)which * 1024 * 1024;
  float scale = (which == 0) ? 0.125f : 1.0f;
  wconv_body(src, d, 1024, 1024, scale, blockIdx.x * 64, blockIdx.y * 64);
}

__global__ __launch_bounds__(256) void wconv_gen_k(const float* __restrict__ W, u16* __restrict__ dst,
                                                   int K, int N) {
  int z = blockIdx.z;
  wconv_body(W + (size_t)z * K * N, dst + (size_t)z * N * K, K, N, 1.0f,
             blockIdx.x * 64, blockIdx.y * 64);
}

__global__ __launch_bounds__(256) void bqkv_k(const float* bq, const float* bk, const float* bv,
                                              float* o) {
  int i = blockIdx.x * 256 + threadIdx.x;  // 18432
  int l = i / 3072, j = i % 3072;
  float v = (j < 1024) ? bq[l * 1024 + j] * 0.125f
                       : (j < 2048 ? bk[l * 1024 + j - 1024] : bv[l * 1024 + j - 2048]);
  o[i] = v;
}

// ---------------- GEMM 128x128x32, 4 waves, 4-buf depth-3 vmcnt pipeline ----------------
// KSPLIT>1: writes bf16 partials (z-th slab of Cv as u16). VTFUSE: V third -> transposed vt.
template <int OBF, int RELU, int KSPLIT, int VTFUSE>
__global__ __launch_bounds__(256) void gemm128_k(const u16* __restrict__ A, const u16* __restrict__ Bt,
                                                 const float* __restrict__ bias, void* __restrict__ Cv,
                                                 int N, int K, u16* __restrict__ vtout) {
  __shared__ u16 As[4][128 * 32];
  __shared__ u16 Bs[4][128 * 32];
  const int t = threadIdx.x, lane = t & 63, wave = t >> 6;
  const int wm = wave >> 1, wn = wave & 1;
  const int lrow = lane & 15, lgrp = lane >> 4;

  const int GX = N >> 7;
  const int nwg = GX * 16;
  int flat = blockIdx.y * GX + blockIdx.x;
  int q = nwg >> 3, r = nwg & 7, xcd = flat & 7, pos = flat >> 3;
  int logical = (xcd < r ? xcd * (q + 1) : r * (q + 1) + (xcd - r) * q) + pos;
  const int m0 = (logical & 15) * 128, n0 = (logical >> 4) * 128;

  const int kseg = K / KSPLIT;
  const int koff = (KSPLIT > 1) ? blockIdx.z * kseg : 0;

  f32x4 acc[4][4];
#pragma unroll
  for (int i = 0; i < 4; ++i)
#pragma unroll
    for (int j = 0; j < 4; ++j) acc[i][j] = (f32x4){0.f, 0.f, 0.f, 0.f};

  const u16* Ag = A + (size_t)m0 * K + koff;
  const u16* Bg = Bt + (size_t)n0 * K + koff;

  auto stage = [&](int buf, int k0) {
#pragma unroll
    for (int rr = 0; rr < 2; ++rr) {
      int s = rr * 256 + t;
      int row = s >> 2, cst = s & 3;
      int csrc = cst ^ ((row >> 1) & 3);
      gload16(Ag + (size_t)row * K + k0 + csrc * 8, &As[buf][s * 8]);
    }
#pragma unroll
    for (int rr = 0; rr < 2; ++rr) {
      int s = rr * 256 + t;
      int row = s >> 2, cst = s & 3;
      int csrc = cst ^ ((row >> 1) & 3);
      gload16(Bg + (size_t)row * K + k0 + csrc * 8, &Bs[buf][s * 8]);
    }
  };

  const int nk = kseg / 32;
  stage(0, 0);
  stage(1, 32);
  stage(2, 64);
  for (int tt = 0; tt < nk; ++tt) {
    if (tt + 2 < nk) asm volatile("s_waitcnt vmcnt(8)" ::: "memory");
    else if (tt + 1 < nk) asm volatile("s_waitcnt vmcnt(4)" ::: "memory");
    else asm volatile("s_waitcnt vmcnt(0)" ::: "memory");
    __builtin_amdgcn_s_barrier();
    __builtin_amdgcn_sched_barrier(0);
    if (tt + 3 < nk) stage((tt + 3) & 3, (tt + 3) * 32);
    const int cur = tt & 3;
    bf16x8 af[4], bfr[4];
#pragma unroll
    for (int i = 0; i < 4; ++i) {
      int row = wm * 64 + i * 16 + lrow;
      int sl = lgrp ^ ((row >> 1) & 3);
      af[i] = *(const bf16x8*)&As[cur][row * 32 + sl * 8];
    }
#pragma unroll
    for (int j = 0; j < 4; ++j) {
      int row = wn * 64 + j * 16 + lrow;
      int sl = lgrp ^ ((row >> 1) & 3);
      bfr[j] = *(const bf16x8*)&Bs[cur][row * 32 + sl * 8];
    }
    __builtin_amdgcn_s_setprio(1);
#pragma unroll
    for (int i = 0; i < 4; ++i)
#pragma unroll
      for (int j = 0; j < 4; ++j)
        acc[i][j] = __builtin_amdgcn_mfma_f32_16x16x32_bf16(af[i], bfr[j], acc[i][j], 0, 0, 0);
    __builtin_amdgcn_s_setprio(0);
  }

  const size_t outoff = (KSPLIT > 1) ? (size_t)blockIdx.z * NTOKS * N : 0;
#pragma unroll
  for (int j = 0; j < 4; ++j) {
    int col = n0 + wn * 64 + j * 16 + lrow;
    float bv = (KSPLIT == 1 || blockIdx.z == 0) ? bias[col] : 0.f;
#pragma unroll
    for (int i = 0; i < 4; ++i) {
      int rowb = m0 + wm * 64 + i * 16 + lgrp * 4;
      if (VTFUSE && col >= 2048) {
        int dg = col - 2048;
        int bb = rowb >> 9, s0 = rowb & 511;
        ushort4 wv;
        wv.x = f2bf(acc[i][j][0] + bv);
        wv.y = f2bf(acc[i][j][1] + bv);
        wv.z = f2bf(acc[i][j][2] + bv);
        wv.w = f2bf(acc[i][j][3] + bv);
        *(ushort4*)&vtout[((size_t)(bb * 1024 + dg)) * 512 + s0] = wv;
      } else if (KSPLIT > 1) {
#pragma unroll
        for (int r = 0; r < 4; ++r)
          ((u16*)Cv)[outoff + (size_t)(rowb + r) * N + col] = f2bf(acc[i][j][r] + bv);
      } else {
#pragma unroll
        for (int r = 0; r < 4; ++r) {
          float v = acc[i][j][r] + bv;
          if (RELU) v = fmaxf(v, 0.f);
          if (OBF)
            ((u16*)Cv)[(size_t)(rowb + r) * N + col] = f2bf(v);
          else
            ((float*)Cv)[(size_t)(rowb + r) * N + col] = v;
        }
      }
    }
  }
}

// ---------------- fused flash attention, NO-MAX softmax (round-16 best config) ----------------
// 3 barriers/iter (the no-barrier shortcut was FALSIFIED in round 10).
#define KPAD 72
__global__ __launch_bounds__(256) void attn_k(const u16* __restrict__ qkv, const u16* __restrict__ vt,
                                              const float* __restrict__ mask, u16* __restrict__ o) {
  __shared__ u16 Ks[64 * KPAD];
  __shared__ u16 Vs[64 * KPAD];
  __shared__ u16 Ps[64 * KPAD];
  const int t = threadIdx.x;
  const int lane = t & 63, wave = t >> 6;
  const int lrow = lane & 15, lgrp = lane >> 4;
  const int qb = blockIdx.x;
  const int bh = blockIdx.y;
  const int b = bh >> 4, hh = bh & 15;

  bf16x8 qf[2];
  const int qrow0 = qb * 64 + wave * 16;
#pragma unroll
  for (int kk = 0; kk < 2; ++kk)
    qf[kk] = *(const bf16x8*)(qkv + (size_t)(b * SEQ + qrow0 + lrow) * 3072 +
                              hh * 64 + kk * 32 + lgrp * 8);

  float lsum[4];
  f32x4 oacc[4];
#pragma unroll
  for (int r = 0; r < 4; ++r) lsum[r] = 0.f;
#pragma unroll
  for (int dn = 0; dn < 4; ++dn) oacc[dn] = (f32x4){0.f, 0.f, 0.f, 0.f};

  const int sr = t >> 3, sc = t & 7;
  for (int it = 0; it < 8; ++it) {
    const int kv0 = it * 64;
#pragma unroll
    for (int half = 0; half < 2; ++half) {
      int r = sr + half * 32;
      uint4 kv4 = *(const uint4*)(qkv + (size_t)(b * SEQ + kv0 + r) * 3072 + 1024 + hh * 64 + sc * 8);
      *(uint4*)(&Ks[r * KPAD + sc * 8]) = kv4;
      uint4 vv4 = *(const uint4*)(vt + (size_t)(bh * 64 + r) * SEQ + kv0 + sc * 8);
      *(uint4*)(&Vs[r * KPAD + sc * 8]) = vv4;
    }
    __syncthreads();

    f32x4 s[4];
#pragma unroll
    for (int nt = 0; nt < 4; ++nt) s[nt] = (f32x4){0.f, 0.f, 0.f, 0.f};
    __builtin_amdgcn_s_setprio(1);
#pragma unroll
    for (int nt = 0; nt < 4; ++nt)
#pragma unroll
      for (int kk = 0; kk < 2; ++kk) {
        bf16x8 kf = *(const bf16x8*)(&Ks[(nt * 16 + lrow) * KPAD + kk * 32 + lgrp * 8]);
        s[nt] = __builtin_amdgcn_mfma_f32_16x16x32_bf16(qf[kk], kf, s[nt], 0, 0, 0);
      }
    __builtin_amdgcn_s_setprio(0);
    float mv[4];
#pragma unroll
    for (int nt = 0; nt < 4; ++nt) mv[nt] = mask[b * SEQ + kv0 + nt * 16 + lrow] * -1e9f;

#pragma unroll
    for (int r = 0; r < 4; ++r) {
      float p0 = __expf(s[0][r] + mv[0]);
      float p1 = __expf(s[1][r] + mv[1]);
      float p2 = __expf(s[2][r] + mv[2]);
      float p3 = __expf(s[3][r] + mv[3]);
      lsum[r] += (p0 + p1) + (p2 + p3);
      int prow = wave * 16 + lgrp * 4 + r;
      Ps[prow * KPAD + 0 + lrow] = f2bf(p0);
      Ps[prow * KPAD + 16 + lrow] = f2bf(p1);
      Ps[prow * KPAD + 32 + lrow] = f2bf(p2);
      Ps[prow * KPAD + 48 + lrow] = f2bf(p3);
    }
    __syncthreads();
    __builtin_amdgcn_s_setprio(1);
#pragma unroll
    for (int kk = 0; kk < 2; ++kk) {
      bf16x8 pf = *(const bf16x8*)(&Ps[(wave * 16 + lrow) * KPAD + kk * 32 + lgrp * 8]);
#pragma unroll
      for (int dn = 0; dn < 4; ++dn) {
        bf16x8 vf = *(const bf16x8*)(&Vs[(dn * 16 + lrow) * KPAD + kk * 32 + lgrp * 8]);
        oacc[dn] = __builtin_amdgcn_mfma_f32_16x16x32_bf16(pf, vf, oacc[dn], 0, 0, 0);
      }
    }
    __builtin_amdgcn_s_setprio(0);
    __syncthreads();
  }
#pragma unroll
  for (int r = 0; r < 4; ++r) {
    lsum[r] += __shfl_xor(lsum[r], 1);
    lsum[r] += __shfl_xor(lsum[r], 2);
    lsum[r] += __shfl_xor(lsum[r], 4);
    lsum[r] += __shfl_xor(lsum[r], 8);
  }
#pragma unroll
  for (int dn = 0; dn < 4; ++dn)
#pragma unroll
    for (int r = 0; r < 4; ++r) {
      int qrow = qrow0 + lgrp * 4 + r;
      o[(size_t)(b * SEQ + qrow) * D_MODEL + hh * 64 + dn * 16 + lrow] =
          f2bf(oacc[dn][r] / lsum[r]);
    }
}

// ---------------- bf16 residual + P bf16 split-K partials + LayerNorm ----------------
// 128 threads/block, 8 elems/thread -> 16B loads (G13). FINAL=1: f32 d_out.
template <int P, int FINAL>
__global__ __launch_bounds__(128) void ln_k(const u16* __restrict__ res, const u16* __restrict__ parts,
                                            const float* __restrict__ g, const float* __restrict__ be,
                                            void* __restrict__ outv) {
  __shared__ float red[4];
  const int row = blockIdx.x, t = threadIdx.x;
  float xv[8];
  {
    u16x8 va = *(const u16x8*)(res + (size_t)row * D_MODEL + t * 8);
#pragma unroll
    for (int j = 0; j < 8; ++j) xv[j] = bf2f((u16)va[j]);
  }
#pragma unroll
  for (int p = 0; p < P; ++p) {
    u16x8 vp = *(const u16x8*)(parts + (size_t)p * NTOKS * D_MODEL + (size_t)row * D_MODEL + t * 8);
#pragma unroll
    for (int j = 0; j < 8; ++j) xv[j] += bf2f((u16)vp[j]);
  }
  float s = 0.f, s2 = 0.f;
#pragma unroll
  for (int j = 0; j < 8; ++j) { s += xv[j]; s2 += xv[j] * xv[j]; }
#pragma unroll
  for (int off = 1; off < 64; off <<= 1) {
    s += __shfl_xor(s, off);
    s2 += __shfl_xor(s2, off);
  }
  const int wave = t >> 6, lane = t & 63;
  if (lane == 0) { red[wave] = s; red[2 + wave] = s2; }
  __syncthreads();
  s = red[0] + red[1];
  s2 = red[2] + red[3];
  float mean = s * (1.f / D_MODEL);
  float var = s2 * (1.f / D_MODEL) - mean * mean;
  float inv = rsqrtf(var + 1e-6f);
  float rv[8];
#pragma unroll
  for (int jj = 0; jj < 2; ++jj) {
    float4 vg = *(const float4*)(g + t * 8 + jj * 4);
    float4 ve = *(const float4*)(be + t * 8 + jj * 4);
    rv[jj * 4 + 0] = (xv[jj * 4 + 0] - mean) * inv * vg.x + ve.x;
    rv[jj * 4 + 1] = (xv[jj * 4 + 1] - mean) * inv * vg.y + ve.y;
    rv[jj * 4 + 2] = (xv[jj * 4 + 2] - mean) * inv * vg.z + ve.z;
    rv[jj * 4 + 3] = (xv[jj * 4 + 3] - mean) * inv * vg.w + ve.w;
  }
  if (FINAL) {
#pragma unroll
    for (int jj = 0; jj < 2; ++jj) {
      float4 r = {rv[jj * 4], rv[jj * 4 + 1], rv[jj * 4 + 2], rv[jj * 4 + 3]};
      *(float4*)((float*)outv + (size_t)row * D_MODEL + t * 8 + jj * 4) = r;
    }
  } else {
    u16x8 w;
#pragma unroll
    for (int j = 0; j < 8; ++j) w[j] = f2bf(rv[j]);
    *(u16x8*)((u16*)outv + (size_t)row * D_MODEL + t * 8) = w;
  }
}

// ---------------- launch ----------------
extern "C" void kernel_launch(void* const* d_in, const int* in_sizes, int n_in,
                              void* d_out, int out_size, void* d_ws, size_t ws_size,
                              hipStream_t stream) {
  const float* x = (const float*)d_in[0];
  const float* mask = (const float*)d_in[1];
  const float* Wq = (const float*)d_in[2];
  const float* bq = (const float*)d_in[3];
  const float* Wk = (const float*)d_in[4];
  const float* bk = (const float*)d_in[5];
  const float* Wv = (const float*)d_in[6];
  const float* bv = (const float*)d_in[7];
  const float* Wo = (const float*)d_in[8];
  const float* bo = (const float*)d_in[9];
  const float* W1 = (const float*)d_in[10];
  const float* b1 = (const float*)d_in[11];
  const float* W2 = (const float*)d_in[12];
  const float* b2 = (const float*)d_in[13];
  const float* g1 = (const float*)d_in[14];
  const float* be1 = (const float*)d_in[15];
  const float* g2 = (const float*)d_in[16];
  const float* be2 = (const float*)d_in[17];
  float* out = (float*)d_out;

  const size_t NTOK = (size_t)BATCH * SEQ;  // 2048
  const size_t ACT = NTOK * D_MODEL;        // 2M
  char* w = (char*)d_ws;
  u16* op = (u16*)w;        w += ACT * 2 * 4;      // split-K bf16 partials x4
  u16* hb = (u16*)w;        w += ACT * 2;          // bf16 residual stream (layer in)
  u16* h1b = (u16*)w;       w += ACT * 2;          // bf16 post-LN1
  u16* qkvb = (u16*)w;      w += NTOK * 3072 * 2;
  u16* vt_ = (u16*)w;       w += ACT * 2;
  u16* obb = (u16*)w;       w += ACT * 2;
  u16* tb = (u16*)w;        w += NTOK * FF * 2;
  u16* wqkv_all = (u16*)w;  w += (size_t)NLAYER * 3072 * 1024 * 2;
  u16* wo_all = (u16*)w;    w += (size_t)NLAYER * 1024 * 1024 * 2;
  u16* w1_all = (u16*)w;    w += (size_t)NLAYER * 4096 * 1024 * 2;
  u16* w2_all = (u16*)w;    w += (size_t)NLAYER * 1024 * 4096 * 2;
  float* bqkv_all = (float*)w; w += (size_t)NLAYER * 3072 * 4;

  posenc_k<<<(int)NTOK, 256, 0, stream>>>(x, hb);
  wconv_qkv_k<<<dim3(16, 16, 18), 256, 0, stream>>>(Wq, Wk, Wv, wqkv_all);
  wconv_gen_k<<<dim3(16, 16, 6), 256, 0, stream>>>(Wo, wo_all, 1024, 1024);
  wconv_gen_k<<<dim3(64, 16, 6), 256, 0, stream>>>(W1, w1_all, 1024, 4096);
  wconv_gen_k<<<dim3(16, 64, 6), 256, 0, stream>>>(W2, w2_all, 4096, 1024);
  bqkv_k<<<72, 256, 0, stream>>>(bq, bk, bv, bqkv_all);

  for (int l = 0; l < NLAYER; ++l) {
    const u16* wqkv_t = wqkv_all + (size_t)l * 3072 * 1024;
    const u16* wo_t = wo_all + (size_t)l * 1024 * 1024;
    const u16* w1_t = w1_all + (size_t)l * 4096 * 1024;
    const u16* w2_t = w2_all + (size_t)l * 1024 * 4096;
    const float* bqkvl = bqkv_all + (size_t)l * 3072;
    const float* bol = bo + (size_t)l * D_MODEL;
    const float* b1l = b1 + (size_t)l * FF;
    const float* b2l = b2 + (size_t)l * D_MODEL;
    const float* g1l = g1 + (size_t)l * D_MODEL;
    const float* be1l = be1 + (size_t)l * D_MODEL;
    const float* g2l = g2 + (size_t)l * D_MODEL;
    const float* be2l = be2 + (size_t)l * D_MODEL;

    gemm128_k<1, 0, 1, 1><<<dim3(24, 16), 256, 0, stream>>>(hb, wqkv_t, bqkvl, qkvb, 3072, 1024, vt_);
    attn_k<<<dim3(8, 64), 256, 0, stream>>>(qkvb, vt_, mask, obb);
    gemm128_k<0, 0, 4, 0><<<dim3(8, 16, 4), 256, 0, stream>>>(obb, wo_t, bol, op, 1024, 1024, nullptr);
    ln_k<4, 0><<<(int)NTOK, 128, 0, stream>>>(hb, op, g1l, be1l, h1b);
    gemm128_k<1, 1, 1, 0><<<dim3(32, 16), 256, 0, stream>>>(h1b, w1_t, b1l, tb, 4096, 1024, nullptr);
    gemm128_k<0, 0, 4, 0><<<dim3(8, 16, 4), 256, 0, stream>>>(tb, w2_t, b2l, op, 1024, 4096, nullptr);
    if (l == NLAYER - 1)
      ln_k<4, 1><<<(int)NTOK, 128, 0, stream>>>(h1b, op, g2l, be2l, out);
    else
      ln_k<4, 0><<<(int)NTOK, 128, 0, stream>>>(h1b, op, g2l, be2l, hb);
  }
}

// Round 19
// 942.749 us; speedup vs baseline: 1.0045x; 1.0005x over previous
//
#include <hip/hip_runtime.h>

typedef __attribute__((ext_vector_type(8))) short bf16x8;
typedef __attribute__((ext_vector_type(4))) float f32x4;
typedef __attribute__((ext_vector_type(8))) unsigned short u16x8;
typedef unsigned short u16;

#define D_MODEL 1024
#define SEQ 512
#define BATCH 4
#define NH 16
#define FF 4096
#define NLAYER 6
#define NTOKS 2048

__device__ __forceinline__ u16 f2bf(float f) {
  unsigned int u = __float_as_uint(f);
  u += 0x7fffu + ((u >> 16) & 1u);
  return (u16)(u >> 16);
}
__device__ __forceinline__ float bf2f(u16 v) {
  return __uint_as_float(((unsigned int)v) << 16);
}

__device__ __forceinline__ void gload16(const void* g, void* lds) {
  __builtin_amdgcn_global_load_lds((const __attribute__((address_space(1))) void*)g,
                                   (__attribute__((address_space(3))) void*)lds, 16, 0, 0);
}

// ---------------- positional encoding: bf16 residual out only ----------------
__global__ __launch_bounds__(256) void posenc_k(const float* __restrict__ x, u16* __restrict__ hb) {
  int row = blockIdx.x;
  int s = row & (SEQ - 1);
  int t = threadIdx.x;
  float4 v = *(const float4*)(x + (size_t)row * D_MODEL + t * 4);
  float r[4] = {v.x, v.y, v.z, v.w};
#pragma unroll
  for (int j = 0; j < 4; ++j) {
    int d = t * 4 + j;
    int p = d >> 1;
    float ang = (float)s * exp2f((float)p * (-2.0f / 1024.0f) * 13.287712379549449f);
    r[j] += (d & 1) ? cosf(ang) : sinf(ang);
  }
  ushort4 ob;
  ob.x = f2bf(r[0]); ob.y = f2bf(r[1]); ob.z = f2bf(r[2]); ob.w = f2bf(r[3]);
  *(ushort4*)(hb + (size_t)row * D_MODEL + t * 4) = ob;
}

// ---------------- weight transpose+convert ----------------
#define WTP 72
__device__ __forceinline__ void wconv_body(const float* __restrict__ src, u16* __restrict__ dst,
                                           int K, int N, float scale, int nb, int kb) {
  __shared__ u16 tile[64 * WTP];
  const int t = threadIdx.x;
#pragma unroll
  for (int rr = 0; rr < 4; ++rr) {
    int k = (t >> 4) + rr * 16;
    int n4 = (t & 15) * 4;
    float4 v = *(const float4*)(src + (size_t)(kb + k) * N + nb + n4);
    tile[(n4 + 0) * WTP + k] = f2bf(v.x * scale);
    tile[(n4 + 1) * WTP + k] = f2bf(v.y * scale);
    tile[(n4 + 2) * WTP + k] = f2bf(v.z * scale);
    tile[(n4 + 3) * WTP + k] = f2bf(v.w * scale);
  }
  __syncthreads();
#pragma unroll
  for (int rr = 0; rr < 2; ++rr) {
    int n = (t >> 3) + rr * 32;
    int kq = (t & 7) * 8;
    uint4 v = *(const uint4*)&tile[n * WTP + kq];
    *(uint4*)&dst[(size_t)(nb + n) * K + kb + kq] = v;
  }
}

__global__ __launch_bounds__(256) void wconv_qkv_k(const float* __restrict__ Wq,
                                                   const float* __restrict__ Wk,
                                                   const float* __restrict__ Wv,
                                                   u16* __restrict__ dst) {
  int z = blockIdx.z, l = z / 3, which = z % 3;
  const float* src = (which == 0 ? Wq : which == 1 ? Wk : Wv) + (size_t)l * 1024 * 1024;
  u16* d = dst + (size_t)l * 3072 * 1024 + (size_t)which * 1024 * 1024;
  float scale = (which == 0) ? 0.125f : 1.0f;
  wconv_body(src, d, 1024, 1024, scale, blockIdx.x * 64, blockIdx.y * 64);
}

__global__ __launch_bounds__(256) void wconv_gen_k(const float* __restrict__ W, u16* __restrict__ dst,
                                                   int K, int N) {
  int z = blockIdx.z;
  wconv_body(W + (size_t)z * K * N, dst + (size_t)z * N * K, K, N, 1.0f,
             blockIdx.x * 64, blockIdx.y * 64);
}

__global__ __launch_bounds__(256) void bqkv_k(const float* bq, const float* bk, const float* bv,
                                              float* o) {
  int i = blockIdx.x * 256 + threadIdx.x;  // 18432
  int l = i / 3072, j = i % 3072;
  float v = (j < 1024) ? bq[l * 1024 + j] * 0.125f
                       : (j < 2048 ? bk[l * 1024 + j - 1024] : bv[l * 1024 + j - 2048]);
  o[i] = v;
}

// ---------------- GEMM 128x128x32, 4 waves, 4-buf depth-3 vmcnt pipeline ----------------
// No setprio here: T5 is null-to-negative on lockstep (non-phase-split) GEMMs (m190).
// KSPLIT>1: writes bf16 partials (z-th slab of Cv as u16). VTFUSE: V third -> transposed vt.
template <int OBF, int RELU, int KSPLIT, int VTFUSE>
__global__ __launch_bounds__(256) void gemm128_k(const u16* __restrict__ A, const u16* __restrict__ Bt,
                                                 const float* __restrict__ bias, void* __restrict__ Cv,
                                                 int N, int K, u16* __restrict__ vtout) {
  __shared__ u16 As[4][128 * 32];
  __shared__ u16 Bs[4][128 * 32];
  const int t = threadIdx.x, lane = t & 63, wave = t >> 6;
  const int wm = wave >> 1, wn = wave & 1;
  const int lrow = lane & 15, lgrp = lane >> 4;

  const int GX = N >> 7;
  const int nwg = GX * 16;
  int flat = blockIdx.y * GX + blockIdx.x;
  int q = nwg >> 3, r = nwg & 7, xcd = flat & 7, pos = flat >> 3;
  int logical = (xcd < r ? xcd * (q + 1) : r * (q + 1) + (xcd - r) * q) + pos;
  const int m0 = (logical & 15) * 128, n0 = (logical >> 4) * 128;

  const int kseg = K / KSPLIT;
  const int koff = (KSPLIT > 1) ? blockIdx.z * kseg : 0;

  f32x4 acc[4][4];
#pragma unroll
  for (int i = 0; i < 4; ++i)
#pragma unroll
    for (int j = 0; j < 4; ++j) acc[i][j] = (f32x4){0.f, 0.f, 0.f, 0.f};

  const u16* Ag = A + (size_t)m0 * K + koff;
  const u16* Bg = Bt + (size_t)n0 * K + koff;

  auto stage = [&](int buf, int k0) {
#pragma unroll
    for (int rr = 0; rr < 2; ++rr) {
      int s = rr * 256 + t;
      int row = s >> 2, cst = s & 3;
      int csrc = cst ^ ((row >> 1) & 3);
      gload16(Ag + (size_t)row * K + k0 + csrc * 8, &As[buf][s * 8]);
    }
#pragma unroll
    for (int rr = 0; rr < 2; ++rr) {
      int s = rr * 256 + t;
      int row = s >> 2, cst = s & 3;
      int csrc = cst ^ ((row >> 1) & 3);
      gload16(Bg + (size_t)row * K + k0 + csrc * 8, &Bs[buf][s * 8]);
    }
  };

  const int nk = kseg / 32;
  stage(0, 0);
  stage(1, 32);
  stage(2, 64);
  for (int tt = 0; tt < nk; ++tt) {
    if (tt + 2 < nk) asm volatile("s_waitcnt vmcnt(8)" ::: "memory");
    else if (tt + 1 < nk) asm volatile("s_waitcnt vmcnt(4)" ::: "memory");
    else asm volatile("s_waitcnt vmcnt(0)" ::: "memory");
    __builtin_amdgcn_s_barrier();
    __builtin_amdgcn_sched_barrier(0);
    if (tt + 3 < nk) stage((tt + 3) & 3, (tt + 3) * 32);
    const int cur = tt & 3;
    bf16x8 af[4], bfr[4];
#pragma unroll
    for (int i = 0; i < 4; ++i) {
      int row = wm * 64 + i * 16 + lrow;
      int sl = lgrp ^ ((row >> 1) & 3);
      af[i] = *(const bf16x8*)&As[cur][row * 32 + sl * 8];
    }
#pragma unroll
    for (int j = 0; j < 4; ++j) {
      int row = wn * 64 + j * 16 + lrow;
      int sl = lgrp ^ ((row >> 1) & 3);
      bfr[j] = *(const bf16x8*)&Bs[cur][row * 32 + sl * 8];
    }
#pragma unroll
    for (int i = 0; i < 4; ++i)
#pragma unroll
      for (int j = 0; j < 4; ++j)
        acc[i][j] = __builtin_amdgcn_mfma_f32_16x16x32_bf16(af[i], bfr[j], acc[i][j], 0, 0, 0);
  }

  const size_t outoff = (KSPLIT > 1) ? (size_t)blockIdx.z * NTOKS * N : 0;
#pragma unroll
  for (int j = 0; j < 4; ++j) {
    int col = n0 + wn * 64 + j * 16 + lrow;
    float bv = (KSPLIT == 1 || blockIdx.z == 0) ? bias[col] : 0.f;
#pragma unroll
    for (int i = 0; i < 4; ++i) {
      int rowb = m0 + wm * 64 + i * 16 + lgrp * 4;
      if (VTFUSE && col >= 2048) {
        int dg = col - 2048;
        int bb = rowb >> 9, s0 = rowb & 511;
        ushort4 wv;
        wv.x = f2bf(acc[i][j][0] + bv);
        wv.y = f2bf(acc[i][j][1] + bv);
        wv.z = f2bf(acc[i][j][2] + bv);
        wv.w = f2bf(acc[i][j][3] + bv);
        *(ushort4*)&vtout[((size_t)(bb * 1024 + dg)) * 512 + s0] = wv;
      } else if (KSPLIT > 1) {
#pragma unroll
        for (int r = 0; r < 4; ++r)
          ((u16*)Cv)[outoff + (size_t)(rowb + r) * N + col] = f2bf(acc[i][j][r] + bv);
      } else {
#pragma unroll
        for (int r = 0; r < 4; ++r) {
          float v = acc[i][j][r] + bv;
          if (RELU) v = fmaxf(v, 0.f);
          if (OBF)
            ((u16*)Cv)[(size_t)(rowb + r) * N + col] = f2bf(v);
          else
            ((float*)Cv)[(size_t)(rowb + r) * N + col] = v;
        }
      }
    }
  }
}

// ---------------- fused flash attention, NO-MAX softmax (best config; setprio kept: m191) ----------------
// 3 barriers/iter (the no-barrier shortcut was FALSIFIED in round 10).
#define KPAD 72
__global__ __launch_bounds__(256) void attn_k(const u16* __restrict__ qkv, const u16* __restrict__ vt,
                                              const float* __restrict__ mask, u16* __restrict__ o) {
  __shared__ u16 Ks[64 * KPAD];
  __shared__ u16 Vs[64 * KPAD];
  __shared__ u16 Ps[64 * KPAD];
  const int t = threadIdx.x;
  const int lane = t & 63, wave = t >> 6;
  const int lrow = lane & 15, lgrp = lane >> 4;
  const int qb = blockIdx.x;
  const int bh = blockIdx.y;
  const int b = bh >> 4, hh = bh & 15;

  bf16x8 qf[2];
  const int qrow0 = qb * 64 + wave * 16;
#pragma unroll
  for (int kk = 0; kk < 2; ++kk)
    qf[kk] = *(const bf16x8*)(qkv + (size_t)(b * SEQ + qrow0 + lrow) * 3072 +
                              hh * 64 + kk * 32 + lgrp * 8);

  float lsum[4];
  f32x4 oacc[4];
#pragma unroll
  for (int r = 0; r < 4; ++r) lsum[r] = 0.f;
#pragma unroll
  for (int dn = 0; dn < 4; ++dn) oacc[dn] = (f32x4){0.f, 0.f, 0.f, 0.f};

  const int sr = t >> 3, sc = t & 7;
  for (int it = 0; it < 8; ++it) {
    const int kv0 = it * 64;
#pragma unroll
    for (int half = 0; half < 2; ++half) {
      int r = sr + half * 32;
      uint4 kv4 = *(const uint4*)(qkv + (size_t)(b * SEQ + kv0 + r) * 3072 + 1024 + hh * 64 + sc * 8);
      *(uint4*)(&Ks[r * KPAD + sc * 8]) = kv4;
      uint4 vv4 = *(const uint4*)(vt + (size_t)(bh * 64 + r) * SEQ + kv0 + sc * 8);
      *(uint4*)(&Vs[r * KPAD + sc * 8]) = vv4;
    }
    __syncthreads();

    f32x4 s[4];
#pragma unroll
    for (int nt = 0; nt < 4; ++nt) s[nt] = (f32x4){0.f, 0.f, 0.f, 0.f};
    __builtin_amdgcn_s_setprio(1);
#pragma unroll
    for (int nt = 0; nt < 4; ++nt)
#pragma unroll
      for (int kk = 0; kk < 2; ++kk) {
        bf16x8 kf = *(const bf16x8*)(&Ks[(nt * 16 + lrow) * KPAD + kk * 32 + lgrp * 8]);
        s[nt] = __builtin_amdgcn_mfma_f32_16x16x32_bf16(qf[kk], kf, s[nt], 0, 0, 0);
      }
    __builtin_amdgcn_s_setprio(0);
    float mv[4];
#pragma unroll
    for (int nt = 0; nt < 4; ++nt) mv[nt] = mask[b * SEQ + kv0 + nt * 16 + lrow] * -1e9f;

#pragma unroll
    for (int r = 0; r < 4; ++r) {
      float p0 = __expf(s[0][r] + mv[0]);
      float p1 = __expf(s[1][r] + mv[1]);
      float p2 = __expf(s[2][r] + mv[2]);
      float p3 = __expf(s[3][r] + mv[3]);
      lsum[r] += (p0 + p1) + (p2 + p3);
      int prow = wave * 16 + lgrp * 4 + r;
      Ps[prow * KPAD + 0 + lrow] = f2bf(p0);
      Ps[prow * KPAD + 16 + lrow] = f2bf(p1);
      Ps[prow * KPAD + 32 + lrow] = f2bf(p2);
      Ps[prow * KPAD + 48 + lrow] = f2bf(p3);
    }
    __syncthreads();
    __builtin_amdgcn_s_setprio(1);
#pragma unroll
    for (int kk = 0; kk < 2; ++kk) {
      bf16x8 pf = *(const bf16x8*)(&Ps[(wave * 16 + lrow) * KPAD + kk * 32 + lgrp * 8]);
#pragma unroll
      for (int dn = 0; dn < 4; ++dn) {
        bf16x8 vf = *(const bf16x8*)(&Vs[(dn * 16 + lrow) * KPAD + kk * 32 + lgrp * 8]);
        oacc[dn] = __builtin_amdgcn_mfma_f32_16x16x32_bf16(pf, vf, oacc[dn], 0, 0, 0);
      }
    }
    __builtin_amdgcn_s_setprio(0);
    __syncthreads();
  }
#pragma unroll
  for (int r = 0; r < 4; ++r) {
    lsum[r] += __shfl_xor(lsum[r], 1);
    lsum[r] += __shfl_xor(lsum[r], 2);
    lsum[r] += __shfl_xor(lsum[r], 4);
    lsum[r] += __shfl_xor(lsum[r], 8);
  }
#pragma unroll
  for (int dn = 0; dn < 4; ++dn)
#pragma unroll
    for (int r = 0; r < 4; ++r) {
      int qrow = qrow0 + lgrp * 4 + r;
      o[(size_t)(b * SEQ + qrow) * D_MODEL + hh * 64 + dn * 16 + lrow] =
          f2bf(oacc[dn][r] / lsum[r]);
    }
}

// ---------------- bf16 residual + P bf16 split-K partials + LayerNorm ----------------
// 128 threads/block, 8 elems/thread -> 16B loads. FINAL=1: f32 d_out.
template <int P, int FINAL>
__global__ __launch_bounds__(128) void ln_k(const u16* __restrict__ res, const u16* __restrict__ parts,
                                            const float* __restrict__ g, const float* __restrict__ be,
                                            void* __restrict__ outv) {
  __shared__ float red[4];
  const int row = blockIdx.x, t = threadIdx.x;
  float xv[8];
  {
    u16x8 va = *(const u16x8*)(res + (size_t)row * D_MODEL + t * 8);
#pragma unroll
    for (int j = 0; j < 8; ++j) xv[j] = bf2f((u16)va[j]);
  }
#pragma unroll
  for (int p = 0; p < P; ++p) {
    u16x8 vp = *(const u16x8*)(parts + (size_t)p * NTOKS * D_MODEL + (size_t)row * D_MODEL + t * 8);
#pragma unroll
    for (int j = 0; j < 8; ++j) xv[j] += bf2f((u16)vp[j]);
  }
  float s = 0.f, s2 = 0.f;
#pragma unroll
  for (int j = 0; j < 8; ++j) { s += xv[j]; s2 += xv[j] * xv[j]; }
#pragma unroll
  for (int off = 1; off < 64; off <<= 1) {
    s += __shfl_xor(s, off);
    s2 += __shfl_xor(s2, off);
  }
  const int wave = t >> 6, lane = t & 63;
  if (lane == 0) { red[wave] = s; red[2 + wave] = s2; }
  __syncthreads();
  s = red[0] + red[1];
  s2 = red[2] + red[3];
  float mean = s * (1.f / D_MODEL);
  float var = s2 * (1.f / D_MODEL) - mean * mean;
  float inv = rsqrtf(var + 1e-6f);
  float rv[8];
#pragma unroll
  for (int jj = 0; jj < 2; ++jj) {
    float4 vg = *(const float4*)(g + t * 8 + jj * 4);
    float4 ve = *(const float4*)(be + t * 8 + jj * 4);
    rv[jj * 4 + 0] = (xv[jj * 4 + 0] - mean) * inv * vg.x + ve.x;
    rv[jj * 4 + 1] = (xv[jj * 4 + 1] - mean) * inv * vg.y + ve.y;
    rv[jj * 4 + 2] = (xv[jj * 4 + 2] - mean) * inv * vg.z + ve.z;
    rv[jj * 4 + 3] = (xv[jj * 4 + 3] - mean) * inv * vg.w + ve.w;
  }
  if (FINAL) {
#pragma unroll
    for (int jj = 0; jj < 2; ++jj) {
      float4 r = {rv[jj * 4], rv[jj * 4 + 1], rv[jj * 4 + 2], rv[jj * 4 + 3]};
      *(float4*)((float*)outv + (size_t)row * D_MODEL + t * 8 + jj * 4) = r;
    }
  } else {
    u16x8 w;
#pragma unroll
    for (int j = 0; j < 8; ++j) w[j] = f2bf(rv[j]);
    *(u16x8*)((u16*)outv + (size_t)row * D_MODEL + t * 8) = w;
  }
}

// ---------------- launch ----------------
extern "C" void kernel_launch(void* const* d_in, const int* in_sizes, int n_in,
                              void* d_out, int out_size, void* d_ws, size_t ws_size,
                              hipStream_t stream) {
  const float* x = (const float*)d_in[0];
  const float* mask = (const float*)d_in[1];
  const float* Wq = (const float*)d_in[2];
  const float* bq = (const float*)d_in[3];
  const float* Wk = (const float*)d_in[4];
  const float* bk = (const float*)d_in[5];
  const float* Wv = (const float*)d_in[6];
  const float* bv = (const float*)d_in[7];
  const float* Wo = (const float*)d_in[8];
  const float* bo = (const float*)d_in[9];
  const float* W1 = (const float*)d_in[10];
  const float* b1 = (const float*)d_in[11];
  const float* W2 = (const float*)d_in[12];
  const float* b2 = (const float*)d_in[13];
  const float* g1 = (const float*)d_in[14];
  const float* be1 = (const float*)d_in[15];
  const float* g2 = (const float*)d_in[16];
  const float* be2 = (const float*)d_in[17];
  float* out = (float*)d_out;

  const size_t NTOK = (size_t)BATCH * SEQ;  // 2048
  const size_t ACT = NTOK * D_MODEL;        // 2M
  char* w = (char*)d_ws;
  u16* op = (u16*)w;        w += ACT * 2 * 4;      // split-K bf16 partials x4
  u16* hb = (u16*)w;        w += ACT * 2;          // bf16 residual stream (layer in)
  u16* h1b = (u16*)w;       w += ACT * 2;          // bf16 post-LN1
  u16* qkvb = (u16*)w;      w += NTOK * 3072 * 2;
  u16* vt_ = (u16*)w;       w += ACT * 2;
  u16* obb = (u16*)w;       w += ACT * 2;
  u16* tb = (u16*)w;        w += NTOK * FF * 2;
  u16* wqkv_all = (u16*)w;  w += (size_t)NLAYER * 3072 * 1024 * 2;
  u16* wo_all = (u16*)w;    w += (size_t)NLAYER * 1024 * 1024 * 2;
  u16* w1_all = (u16*)w;    w += (size_t)NLAYER * 4096 * 1024 * 2;
  u16* w2_all = (u16*)w;    w += (size_t)NLAYER * 1024 * 4096 * 2;
  float* bqkv_all = (float*)w; w += (size_t)NLAYER * 3072 * 4;

  posenc_k<<<(int)NTOK, 256, 0, stream>>>(x, hb);
  wconv_qkv_k<<<dim3(16, 16, 18), 256, 0, stream>>>(Wq, Wk, Wv, wqkv_all);
  wconv_gen_k<<<dim3(16, 16, 6), 256, 0, stream>>>(Wo, wo_all, 1024, 1024);
  wconv_gen_k<<<dim3(64, 16, 6), 256, 0, stream>>>(W1, w1_all, 1024, 4096);
  wconv_gen_k<<<dim3(16, 64, 6), 256, 0, stream>>>(W2, w2_all, 4096, 1024);
  bqkv_k<<<72, 256, 0, stream>>>(bq, bk, bv, bqkv_all);

  for (int l = 0; l < NLAYER; ++l) {
    const u16* wqkv_t = wqkv_all + (size_t)l * 3072 * 1024;
    const u16* wo_t = wo_all + (size_t)l * 1024 * 1024;
    const u16* w1_t = w1_all + (size_t)l * 4096 * 1024;
    const u16* w2_t = w2_all + (size_t)l * 1024 * 4096;
    const float* bqkvl = bqkv_all + (size_t)l * 3072;
    const float* bol = bo + (size_t)l * D_MODEL;
    const float* b1l = b1 + (size_t)l * FF;
    const float* b2l = b2 + (size_t)l * D_MODEL;
    const float* g1l = g1 + (size_t)l * D_MODEL;
    const float* be1l = be1 + (size_t)l * D_MODEL;
    const float* g2l = g2 + (size_t)l * D_MODEL;
    const float* be2l = be2 + (size_t)l * D_MODEL;

    gemm128_k<1, 0, 1, 1><<<dim3(24, 16), 256, 0, stream>>>(hb, wqkv_t, bqkvl, qkvb, 3072, 1024, vt_);
    attn_k<<<dim3(8, 64), 256, 0, stream>>>(qkvb, vt_, mask, obb);
    gemm128_k<0, 0, 4, 0><<<dim3(8, 16, 4), 256, 0, stream>>>(obb, wo_t, bol, op, 1024, 1024, nullptr);
    ln_k<4, 0><<<(int)NTOK, 128, 0, stream>>>(hb, op, g1l, be1l, h1b);
    gemm128_k<1, 1, 1, 0><<<dim3(32, 16), 256, 0, stream>>>(h1b, w1_t, b1l, tb, 4096, 1024, nullptr);
    gemm128_k<0, 0, 4, 0><<<dim3(8, 16, 4), 256, 0, stream>>>(tb, w2_t, b2l, op, 1024, 4096, nullptr);
    if (l == NLAYER - 1)
      ln_k<4, 1><<<(int)NTOK, 128, 0, stream>>>(h1b, op, g2l, be2l, out);
    else
      ln_k<4, 0><<<(int)NTOK, 128, 0, stream>>>(h1b, op, g2l, be2l, hb);
  }
}